// Round 12
// baseline (317.100 us; speedup 1.0000x reference)
//
#include <hip/hip_runtime.h>
#include <hip/hip_bf16.h>
#include <stdint.h>

#define BB 2
#define SS 2048
#define HH 1024
#define NHH 16
#define HDD 64
#define MM (BB*SS)      // 4096
#define N1 (3*HH)       // 3072
#define NT (SS/64)      // 32 kv tiles
#define LOG2E 1.44269504f

using bf16 = __hip_bfloat16;
typedef __attribute__((ext_vector_type(8))) short bf16x8;
typedef __attribute__((ext_vector_type(4))) float f32x4;

__device__ inline unsigned short f2bfu(float f) {
  union { bf16 h; unsigned short u; } c;
  c.h = __float2bfloat16(f);
  return c.u;
}

// hardware packed f32->bf16 (RNE), src0 -> low16, src1 -> high16 (T12 recipe)
__device__ inline unsigned int cvtpk(float lo, float hi) {
  unsigned int r;
  asm("v_cvt_pk_bf16_f32 %0, %1, %2" : "=v"(r) : "v"(lo), "v"(hi));
  return r;
}

__device__ inline void load_lds16(const void* g, void* l) {
  __builtin_amdgcn_global_load_lds(
      (const __attribute__((address_space(1))) void*)g,
      (__attribute__((address_space(3))) void*)l, 16, 0, 0);
}

__device__ inline f32x4 mfma16(bf16x8 a, bf16x8 b, f32x4 c) {
  return __builtin_amdgcn_mfma_f32_16x16x32_bf16(a, b, c, 0, 0, 0);
}

// ---------------- fp32 -> bf16 convert ----------------
__global__ __launch_bounds__(256) void cvt_f32_bf16(const float* __restrict__ in,
                                                    unsigned short* __restrict__ out,
                                                    int n4) {
  int i = blockIdx.x * blockDim.x + threadIdx.x;
  int st = gridDim.x * blockDim.x;
  for (; i < n4; i += st) {
    float4 v = reinterpret_cast<const float4*>(in)[i];
    ushort4 o;
    o.x = f2bfu(v.x); o.y = f2bfu(v.y); o.z = f2bfu(v.z); o.w = f2bfu(v.w);
    reinterpret_cast<ushort4*>(out)[i] = o;
  }
}

// ---------------- mask tile flags: 1 if 64x64 tile is all ones ----------------
__global__ __launch_bounds__(256) void mask_flags_kernel(const float* __restrict__ mask,
                                                         unsigned char* __restrict__ flags) {
  int t = blockIdx.x;
  int b = t >> 10, qt = (t >> 5) & 31, kt = t & 31;
  const float* mb = mask + ((size_t)b * SS + qt * 64) * SS + kt * 64;
  int row = threadIdx.x >> 2, c0 = (threadIdx.x & 3) * 16;
  int ok = 1;
#pragma unroll
  for (int j = 0; j < 4; ++j) {
    float4 v = *reinterpret_cast<const float4*>(mb + (size_t)row * SS + c0 + j * 4);
    ok &= (v.x == 1.f) & (v.y == 1.f) & (v.z == 1.f) & (v.w == 1.f);
  }
  ok = __all(ok);
  __shared__ int s[4];
  if ((threadIdx.x & 63) == 0) s[threadIdx.x >> 6] = ok;
  __syncthreads();
  if (threadIdx.x == 0) flags[t] = (unsigned char)(s[0] & s[1] & s[2] & s[3]);
}

// ---------------- V transpose: mixed V-cols -> vT[b][h][d][s] ----------------
__global__ __launch_bounds__(256) void vtrans_kernel(const unsigned short* __restrict__ mixed,
                                                     unsigned short* __restrict__ vT) {
  __shared__ unsigned short t[64 * 72];
  const int st = blockIdx.x, bh = blockIdx.y;
  const int b = bh >> 4, h = bh & 15;
  const int r = threadIdx.x >> 2, c0 = (threadIdx.x & 3) * 16;

  const unsigned short* src = mixed + ((size_t)(b * SS) + st * 64) * N1 + h * 192 + 128;
  union { bf16x8 v; unsigned short u[8]; } A, B;
  A.v = *reinterpret_cast<const bf16x8*>(src + (size_t)r * N1 + c0);
  B.v = *reinterpret_cast<const bf16x8*>(src + (size_t)r * N1 + c0 + 8);
#pragma unroll
  for (int j = 0; j < 8; ++j) t[(c0 + j) * 72 + r] = A.u[j];
#pragma unroll
  for (int j = 0; j < 8; ++j) t[(c0 + 8 + j) * 72 + r] = B.u[j];
  __syncthreads();

  unsigned short* dst = vT + ((size_t)bh * HDD + r) * SS + st * 64 + c0;
  bf16x8 o0 = *reinterpret_cast<const bf16x8*>(&t[r * 72 + c0]);
  bf16x8 o1 = *reinterpret_cast<const bf16x8*>(&t[r * 72 + c0 + 8]);
  *reinterpret_cast<bf16x8*>(dst) = o0;
  *reinterpret_cast<bf16x8*>(dst + 8) = o1;
}

// ---------------- GEMM: C[m][n] = sum_k A[m][k]*Bt[n][k] + bias[n] ----------------
template <bool OUT_BF16>
__global__ __launch_bounds__(256) void gemm_bt(const unsigned short* __restrict__ A,
                                               const unsigned short* __restrict__ Bt,
                                               const float* __restrict__ bias,
                                               void* __restrict__ Cv,
                                               int Ndim, int Kdim) {
  __shared__ __align__(16) unsigned short As[128 * 32];
  __shared__ __align__(16) unsigned short Bs[128 * 32];

  const int tid = threadIdx.x;
  const int wave = tid >> 6, lane = tid & 63;
  const int m0 = blockIdx.x * 128;
  const int n0 = blockIdx.y * 128;
  const int wm = (wave >> 1) * 64, wn = (wave & 1) * 64;
  const int lrow = lane & 15;
  const int lk8 = (lane >> 4) * 8;
  const int r4 = (lane >> 4) * 4;

  f32x4 acc[4][4];
  const f32x4 z = {0.f, 0.f, 0.f, 0.f};
  for (int i = 0; i < 4; ++i)
    for (int j = 0; j < 4; ++j) acc[i][j] = z;

  for (int k0 = 0; k0 < Kdim; k0 += 32) {
#pragma unroll
    for (int it = 0; it < 2; ++it) {
      int idx = it * 256 + tid;
      int row = idx >> 2, seg = idx & 3;
      load_lds16(A + (size_t)(m0 + row) * Kdim + k0 + seg * 8, &As[row * 32 + seg * 8]);
      load_lds16(Bt + (size_t)(n0 + row) * Kdim + k0 + seg * 8, &Bs[row * 32 + seg * 8]);
    }
    __syncthreads();

    bf16x8 af[4], bfr[4];
#pragma unroll
    for (int i = 0; i < 4; ++i)
      af[i] = *reinterpret_cast<const bf16x8*>(&As[(wm + i * 16 + lrow) * 32 + lk8]);
#pragma unroll
    for (int j = 0; j < 4; ++j)
      bfr[j] = *reinterpret_cast<const bf16x8*>(&Bs[(wn + j * 16 + lrow) * 32 + lk8]);
#pragma unroll
    for (int i = 0; i < 4; ++i)
#pragma unroll
      for (int j = 0; j < 4; ++j)
        acc[i][j] = mfma16(af[i], bfr[j], acc[i][j]);
    __syncthreads();
  }

#pragma unroll
  for (int i = 0; i < 4; ++i) {
#pragma unroll
    for (int j = 0; j < 4; ++j) {
      int col = n0 + wn + j * 16 + lrow;
      float bv = bias[col];
#pragma unroll
      for (int r = 0; r < 4; ++r) {
        int row = m0 + wm + i * 16 + r4 + r;
        float v = acc[i][j][r] + bv;
        if (OUT_BF16) {
          ((unsigned short*)Cv)[(size_t)row * Ndim + col] = f2bfu(v);
        } else {
          ((float*)Cv)[(size_t)row * Ndim + col] = v;
        }
      }
    }
  }
}

// ---------------- Flash attention: R9 structure + V in registers (T14) ----------------
// Block 256 = 4 waves; Q-tile 64 (wave owns 16 q-rows); KVBLK 64; grid (32, B*NH).
// Swapped QK^T, max-free softmax, 2x-unrolled kt loop. V is NOT staged in LDS:
// each lane prefetches its 8 PV B-fragments (16B contiguous from linear vT[d][s])
// into registers for the NEXT tile while computing the current one. LDS 24KB.
__global__ __launch_bounds__(256, 4) void attn_kernel(const unsigned short* __restrict__ mixed,
                                                      const unsigned short* __restrict__ vT,
                                                      const float* __restrict__ mask,
                                                      const unsigned char* __restrict__ flags,
                                                      unsigned short* __restrict__ ctx) {
  __shared__ __align__(16) unsigned short Ks[2][64 * 64];
  __shared__ __align__(16) unsigned short QP[64 * 64];      // Q tile, then P (per-wave)

  const int tid = threadIdx.x, wave = tid >> 6, lane = tid & 63;
  const int ql = lane & 15;
  const int g = lane >> 4;
  const int q0 = blockIdx.x * 64;
  const int bh = blockIdx.y;
  const int b = bh / NHH, hh = bh % NHH;

  const unsigned short* qbase = mixed + (size_t)(b * SS) * N1 + hh * 192;
  const unsigned short* kbase = qbase + 64;
  const unsigned short* vtbase = vT + ((size_t)(b * NHH + hh) * HDD) * SS;  // [d][s]
  const float* mbase = mask + (size_t)b * SS * SS;
  const unsigned char* fl = flags + ((size_t)b * 32 + blockIdx.x) * 32;

  const int srow = tid >> 3, sseg = tid & 7;
  const int swst = (sseg ^ (srow & 7)) << 3;

  // ---- prologue: stage Q, K0 (LDS); V0 -> registers ----
  load_lds16(qbase + (size_t)(q0 + srow) * N1 + swst, &QP[srow * 64 + sseg * 8]);
  load_lds16(qbase + (size_t)(q0 + 32 + srow) * N1 + swst, &QP[(32 + srow) * 64 + sseg * 8]);
  load_lds16(kbase + (size_t)srow * N1 + swst, &Ks[0][srow * 64 + sseg * 8]);
  load_lds16(kbase + (size_t)(32 + srow) * N1 + swst, &Ks[0][(32 + srow) * 64 + sseg * 8]);

  // per-lane V pointers: fragment (fd, kb): vT[(fd*16+ql)][kt*64 + kb*32 + g*8 .. +7]
  const unsigned short* vp0 = vtbase + (size_t)(0 * 16 + ql) * SS + g * 8;
  const unsigned short* vp1 = vtbase + (size_t)(1 * 16 + ql) * SS + g * 8;
  const unsigned short* vp2 = vtbase + (size_t)(2 * 16 + ql) * SS + g * 8;
  const unsigned short* vp3 = vtbase + (size_t)(3 * 16 + ql) * SS + g * 8;

  bf16x8 vrA[8], vrB[8];
  vrA[0] = *reinterpret_cast<const bf16x8*>(vp0);
  vrA[1] = *reinterpret_cast<const bf16x8*>(vp1);
  vrA[2] = *reinterpret_cast<const bf16x8*>(vp2);
  vrA[3] = *reinterpret_cast<const bf16x8*>(vp3);
  vrA[4] = *reinterpret_cast<const bf16x8*>(vp0 + 32);
  vrA[5] = *reinterpret_cast<const bf16x8*>(vp1 + 32);
  vrA[6] = *reinterpret_cast<const bf16x8*>(vp2 + 32);
  vrA[7] = *reinterpret_cast<const bf16x8*>(vp3 + 32);
  vp0 += 64; vp1 += 64; vp2 += 64; vp3 += 64;
  __syncthreads();

  // ---- hoist Q fragments ----
  const int qrow = wave * 16 + ql;
  const bf16x8 qf0 = *reinterpret_cast<const bf16x8*>(
      &QP[qrow * 64 + ((g ^ (qrow & 7)) << 3)]);
  const bf16x8 qf1 = *reinterpret_cast<const bf16x8*>(
      &QP[qrow * 64 + (((g + 4) ^ (qrow & 7)) << 3)]);
  __syncthreads();   // everyone done reading Q before P overwrites it

  // ---- precomputed loop-invariant LDS pointers ----
  const int s0 = (g ^ (ql & 7)) << 3;
  const int s1 = ((g + 4) ^ (ql & 7)) << 3;
  const unsigned short* KrA = &Ks[0][ql * 64 + s0];   // + CUR*4096 + n*1024
  const unsigned short* KrB = &Ks[0][ql * 64 + s1];
  unsigned short* Ps = &QP[wave * 1024];
  const int X = (ql & 7) << 3;
  unsigned short* Pw0 = &Ps[ql * 64 + ((4 * g) ^ X)];
  unsigned short* Pw1 = &Ps[ql * 64 + ((16 + 4 * g) ^ X)];
  unsigned short* Pw2 = &Ps[ql * 64 + ((32 + 4 * g) ^ X)];
  unsigned short* Pw3 = &Ps[ql * 64 + ((48 + 4 * g) ^ X)];
  const unsigned short* Pr0 = &Ps[ql * 64 + ((8 * g) ^ X)];
  const unsigned short* Pr1 = &Ps[ql * 64 + ((32 + 8 * g) ^ X)];

  // ---- loop-carried global prefetch pointer (K) ----
  const unsigned short* kpre = kbase + (size_t)(64 + srow) * N1 + swst;

  f32x4 oacc[4];
  const f32x4 z = {0.f, 0.f, 0.f, 0.f};
  for (int fd = 0; fd < 4; ++fd) oacc[fd] = z;
  float lsum = 0.f;
  const float C2 = 0.125f * LOG2E;

#define TILE_BODY(CUR_, KT_, HAVENEXT_, VCUR, VNXT)                             \
  {                                                                             \
    const int kt_ = (KT_);                                                      \
    if (HAVENEXT_) {                                                            \
      load_lds16(kpre, &Ks[(CUR_)^1][srow * 64 + sseg * 8]);                    \
      load_lds16(kpre + 32 * N1, &Ks[(CUR_)^1][(32 + srow) * 64 + sseg * 8]);   \
      VNXT[0] = *reinterpret_cast<const bf16x8*>(vp0);                          \
      VNXT[1] = *reinterpret_cast<const bf16x8*>(vp1);                          \
      VNXT[2] = *reinterpret_cast<const bf16x8*>(vp2);                          \
      VNXT[3] = *reinterpret_cast<const bf16x8*>(vp3);                          \
      VNXT[4] = *reinterpret_cast<const bf16x8*>(vp0 + 32);                     \
      VNXT[5] = *reinterpret_cast<const bf16x8*>(vp1 + 32);                     \
      VNXT[6] = *reinterpret_cast<const bf16x8*>(vp2 + 32);                     \
      VNXT[7] = *reinterpret_cast<const bf16x8*>(vp3 + 32);                     \
    }                                                                           \
    kpre += 64 * N1;                                                            \
    vp0 += 64; vp1 += 64; vp2 += 64; vp3 += 64;                                 \
    f32x4 sacc[4];                                                              \
    __builtin_amdgcn_s_setprio(1);                                              \
    _Pragma("unroll")                                                           \
    for (int n = 0; n < 4; ++n) {                                               \
      bf16x8 k0 = *reinterpret_cast<const bf16x8*>(KrA + (CUR_)*4096 + n*1024); \
      bf16x8 k1 = *reinterpret_cast<const bf16x8*>(KrB + (CUR_)*4096 + n*1024); \
      sacc[n] = mfma16(k0, qf0, z);                                             \
      sacc[n] = mfma16(k1, qf1, sacc[n]);                                       \
    }                                                                           \
    __builtin_amdgcn_s_setprio(0);                                              \
    const bool allones = fl[kt_] != 0;                                          \
    float pv[4][4];                                                             \
    if (allones) {                                                              \
      _Pragma("unroll")                                                         \
      for (int n = 0; n < 4; ++n)                                               \
        _Pragma("unroll")                                                       \
        for (int r = 0; r < 4; ++r)                                             \
          pv[n][r] = exp2f(sacc[n][r] * C2);                                    \
    } else {                                                                    \
      int qq = q0 + wave * 16 + ql;                                             \
      _Pragma("unroll")                                                         \
      for (int n = 0; n < 4; ++n)                                               \
        _Pragma("unroll")                                                       \
        for (int r = 0; r < 4; ++r) {                                           \
          int kk = kt_ * 64 + 16 * n + 4 * g + r;                               \
          float mv = mbase[(size_t)qq * SS + kk];                               \
          float s = sacc[n][r] * 0.125f;                                        \
          pv[n][r] = exp2f((s * mv - 10000.f * (1.f - mv)) * LOG2E);            \
        }                                                                       \
    }                                                                           \
    {                                                                           \
      float t00 = (pv[0][0] + pv[0][1]) + (pv[0][2] + pv[0][3]);                \
      float t01 = (pv[1][0] + pv[1][1]) + (pv[1][2] + pv[1][3]);                \
      float t10 = (pv[2][0] + pv[2][1]) + (pv[2][2] + pv[2][3]);                \
      float t11 = (pv[3][0] + pv[3][1]) + (pv[3][2] + pv[3][3]);                \
      lsum += (t00 + t01) + (t10 + t11);                                        \
    }                                                                           \
    { uint2 w; w.x = cvtpk(pv[0][0], pv[0][1]); w.y = cvtpk(pv[0][2], pv[0][3]);\
      *reinterpret_cast<uint2*>(Pw0) = w; }                                     \
    { uint2 w; w.x = cvtpk(pv[1][0], pv[1][1]); w.y = cvtpk(pv[1][2], pv[1][3]);\
      *reinterpret_cast<uint2*>(Pw1) = w; }                                     \
    { uint2 w; w.x = cvtpk(pv[2][0], pv[2][1]); w.y = cvtpk(pv[2][2], pv[2][3]);\
      *reinterpret_cast<uint2*>(Pw2) = w; }                                     \
    { uint2 w; w.x = cvtpk(pv[3][0], pv[3][1]); w.y = cvtpk(pv[3][2], pv[3][3]);\
      *reinterpret_cast<uint2*>(Pw3) = w; }                                     \
    bf16x8 pa0 = *reinterpret_cast<const bf16x8*>(Pr0);                         \
    bf16x8 pa1 = *reinterpret_cast<const bf16x8*>(Pr1);                         \
    __builtin_amdgcn_s_setprio(1);                                              \
    _Pragma("unroll")                                                           \
    for (int fd = 0; fd < 4; ++fd) {                                            \
      oacc[fd] = mfma16(pa0, VCUR[fd], oacc[fd]);                               \
      oacc[fd] = mfma16(pa1, VCUR[4 + fd], oacc[fd]);                           \
    }                                                                           \
    __builtin_amdgcn_s_setprio(0);                                              \
    __syncthreads();                                                            \
  }

  for (int kt = 0; kt < NT; kt += 2) {
    TILE_BODY(0, kt, true, vrA, vrB)       // kt <= 30 -> kt+1 < 32 always
    TILE_BODY(1, kt + 1, (kt + 2 < NT), vrB, vrA)
  }
#undef TILE_BODY

  // ---- epilogue: reduce l across groups, gather per-row, store ----
  float lrun = lsum;
  lrun += __shfl_xor(lrun, 16, 64);
  lrun += __shfl_xor(lrun, 32, 64);
  float invl = 1.f / lrun;   // valid for q = ql at this lane
#pragma unroll
  for (int r = 0; r < 4; ++r) {
    float inv = __shfl(invl, g * 4 + r, 64);
    int qq = q0 + wave * 16 + g * 4 + r;
    unsigned short* cp = ctx + (size_t)(b * SS + qq) * HH + hh * HDD;
#pragma unroll
    for (int fd = 0; fd < 4; ++fd)
      cp[fd * 16 + ql] = f2bfu(oacc[fd][r] * inv);
  }
}

extern "C" void kernel_launch(void* const* d_in, const int* in_sizes, int n_in,
                              void* d_out, int out_size, void* d_ws, size_t ws_size,
                              hipStream_t stream) {
  const float* hs      = (const float*)d_in[0];
  const float* mask    = (const float*)d_in[1];
  const float* qkv_w   = (const float*)d_in[2];
  const float* qkv_b   = (const float*)d_in[3];
  const float* dense_w = (const float*)d_in[4];
  const float* dense_b = (const float*)d_in[5];
  float* out = (float*)d_out;

  char* ws = (char*)d_ws;
  unsigned short* hs_b     = (unsigned short*)(ws);                 // 4096x1024 (8MB)
  unsigned short* qkvw_b   = (unsigned short*)(ws + 8388608);       // 3072x1024 (6MB)
  unsigned short* densew_b = (unsigned short*)(ws + 14680064);      // 1024x1024 (2MB)
  unsigned short* mixed_b  = (unsigned short*)(ws + 16777216);      // 4096x3072 (24MB)
  unsigned short* ctx_b    = (unsigned short*)(ws + 41943040);      // 4096x1024 (8MB)
  unsigned char*  flags    = (unsigned char*)(ws + 50331648);       // 2048 B
  unsigned short* vT_b     = (unsigned short*)(ws + 50335744);      // 8MB

  cvt_f32_bf16<<<2048, 256, 0, stream>>>(hs, hs_b, (MM * HH) / 4);
  cvt_f32_bf16<<<2048, 256, 0, stream>>>(qkv_w, qkvw_b, (N1 * HH) / 4);
  cvt_f32_bf16<<<1024, 256, 0, stream>>>(dense_w, densew_b, (HH * HH) / 4);
  mask_flags_kernel<<<BB * 32 * 32, 256, 0, stream>>>(mask, flags);

  gemm_bt<true><<<dim3(MM / 128, N1 / 128), 256, 0, stream>>>(
      hs_b, qkvw_b, qkv_b, mixed_b, N1, HH);

  vtrans_kernel<<<dim3(SS / 64, BB * NHH), 256, 0, stream>>>(mixed_b, vT_b);

  attn_kernel<<<dim3(SS / 64, BB * NHH), 256, 0, stream>>>(
      mixed_b, vT_b, mask, flags, ctx_b);

  gemm_bt<false><<<dim3(MM / 128, HH / 128), 256, 0, stream>>>(
      ctx_b, densew_b, dense_b, out, HH, HH);
}

// Round 13
// 149.278 us; speedup vs baseline: 2.1242x; 2.1242x over previous
//
#include <hip/hip_runtime.h>
#include <hip/hip_bf16.h>
#include <stdint.h>

#define BB 2
#define SS 2048
#define HH 1024
#define NHH 16
#define HDD 64
#define MM (BB*SS)      // 4096
#define N1 (3*HH)       // 3072
#define NT (SS/64)      // 32 kv tiles
#define LOG2E 1.44269504f

using bf16 = __hip_bfloat16;
typedef __attribute__((ext_vector_type(8))) short bf16x8;
typedef __attribute__((ext_vector_type(4))) float f32x4;

__device__ inline unsigned short f2bfu(float f) {
  union { bf16 h; unsigned short u; } c;
  c.h = __float2bfloat16(f);
  return c.u;
}

// hardware packed f32->bf16 (RNE), src0 -> low16, src1 -> high16 (T12 recipe)
__device__ inline unsigned int cvtpk(float lo, float hi) {
  unsigned int r;
  asm("v_cvt_pk_bf16_f32 %0, %1, %2" : "=v"(r) : "v"(lo), "v"(hi));
  return r;
}

__device__ inline void load_lds16(const void* g, void* l) {
  __builtin_amdgcn_global_load_lds(
      (const __attribute__((address_space(1))) void*)g,
      (__attribute__((address_space(3))) void*)l, 16, 0, 0);
}

__device__ inline f32x4 mfma16(bf16x8 a, bf16x8 b, f32x4 c) {
  return __builtin_amdgcn_mfma_f32_16x16x32_bf16(a, b, c, 0, 0, 0);
}

// ---------------- fused fp32 -> bf16 convert (3 buffers, one launch) ----------------
__global__ __launch_bounds__(256) void cvt3_f32_bf16(const float* __restrict__ a,
                                                     unsigned short* __restrict__ ao, int na4,
                                                     const float* __restrict__ bsrc,
                                                     unsigned short* __restrict__ bo, int nb4,
                                                     const float* __restrict__ c,
                                                     unsigned short* __restrict__ co, int nc4) {
  int total = na4 + nb4 + nc4;
  int st = gridDim.x * blockDim.x;
  for (int i = blockIdx.x * blockDim.x + threadIdx.x; i < total; i += st) {
    const float* in; unsigned short* out; int j = i;
    if (j < na4) { in = a; out = ao; }
    else if (j < na4 + nb4) { j -= na4; in = bsrc; out = bo; }
    else { j -= na4 + nb4; in = c; out = co; }
    float4 v = reinterpret_cast<const float4*>(in)[j];
    ushort4 o;
    o.x = f2bfu(v.x); o.y = f2bfu(v.y); o.z = f2bfu(v.z); o.w = f2bfu(v.w);
    reinterpret_cast<ushort4*>(out)[j] = o;
  }
}

// ---------------- mask tile flags: 1 if 64x64 tile is all ones ----------------
__global__ __launch_bounds__(256) void mask_flags_kernel(const float* __restrict__ mask,
                                                         unsigned char* __restrict__ flags) {
  int t = blockIdx.x;
  int b = t >> 10, qt = (t >> 5) & 31, kt = t & 31;
  const float* mb = mask + ((size_t)b * SS + qt * 64) * SS + kt * 64;
  int row = threadIdx.x >> 2, c0 = (threadIdx.x & 3) * 16;
  int ok = 1;
#pragma unroll
  for (int j = 0; j < 4; ++j) {
    float4 v = *reinterpret_cast<const float4*>(mb + (size_t)row * SS + c0 + j * 4);
    ok &= (v.x == 1.f) & (v.y == 1.f) & (v.z == 1.f) & (v.w == 1.f);
  }
  ok = __all(ok);
  __shared__ int s[4];
  if ((threadIdx.x & 63) == 0) s[threadIdx.x >> 6] = ok;
  __syncthreads();
  if (threadIdx.x == 0) flags[t] = (unsigned char)(s[0] & s[1] & s[2] & s[3]);
}

// ---------------- V transpose: mixed V-cols -> vT[b][h][d][s] ----------------
__global__ __launch_bounds__(256) void vtrans_kernel(const unsigned short* __restrict__ mixed,
                                                     unsigned short* __restrict__ vT) {
  __shared__ unsigned short t[64 * 72];
  const int st = blockIdx.x, bh = blockIdx.y;
  const int b = bh >> 4, h = bh & 15;
  const int r = threadIdx.x >> 2, c0 = (threadIdx.x & 3) * 16;

  const unsigned short* src = mixed + ((size_t)(b * SS) + st * 64) * N1 + h * 192 + 128;
  union { bf16x8 v; unsigned short u[8]; } A, B;
  A.v = *reinterpret_cast<const bf16x8*>(src + (size_t)r * N1 + c0);
  B.v = *reinterpret_cast<const bf16x8*>(src + (size_t)r * N1 + c0 + 8);
#pragma unroll
  for (int j = 0; j < 8; ++j) t[(c0 + j) * 72 + r] = A.u[j];
#pragma unroll
  for (int j = 0; j < 8; ++j) t[(c0 + 8 + j) * 72 + r] = B.u[j];
  __syncthreads();

  unsigned short* dst = vT + ((size_t)bh * HDD + r) * SS + st * 64 + c0;
  bf16x8 o0 = *reinterpret_cast<const bf16x8*>(&t[r * 72 + c0]);
  bf16x8 o1 = *reinterpret_cast<const bf16x8*>(&t[r * 72 + c0 + 8]);
  *reinterpret_cast<bf16x8*>(dst) = o0;
  *reinterpret_cast<bf16x8*>(dst + 8) = o1;
}

// ---------------- GEMM: C[m][n] = sum_k A[m][k]*Bt[n][k] + bias[n] ----------------
// 128x128 tile, BK=64 (half the barriers of BK=32), XOR-swizzled LDS (same
// verified pattern as attn staging): stage source col-seg pre-XORed with row&7,
// fragment reads XOR with lrow&7 (row&7 == lrow&7 since 16 | (wm + i*16)).
template <bool OUT_BF16>
__global__ __launch_bounds__(256) void gemm_bt(const unsigned short* __restrict__ A,
                                               const unsigned short* __restrict__ Bt,
                                               const float* __restrict__ bias,
                                               void* __restrict__ Cv,
                                               int Ndim, int Kdim) {
  __shared__ __align__(16) unsigned short As[128 * 64];
  __shared__ __align__(16) unsigned short Bs[128 * 64];

  const int tid = threadIdx.x;
  const int wave = tid >> 6, lane = tid & 63;
  const int m0 = blockIdx.x * 128;
  const int n0 = blockIdx.y * 128;
  const int wm = (wave >> 1) * 64, wn = (wave & 1) * 64;
  const int lrow = lane & 15;
  const int g = lane >> 4;            // 0..3 col-seg group
  const int r4 = (lane >> 4) * 4;
  const int x0 = (g ^ (lrow & 7)) << 3;        // half-0 read seg offset (elems)
  const int x1 = ((g + 4) ^ (lrow & 7)) << 3;  // half-1

  f32x4 acc[4][4];
  const f32x4 z = {0.f, 0.f, 0.f, 0.f};
  for (int i = 0; i < 4; ++i)
    for (int j = 0; j < 4; ++j) acc[i][j] = z;

  for (int k0 = 0; k0 < Kdim; k0 += 64) {
#pragma unroll
    for (int it = 0; it < 4; ++it) {
      int idx = it * 256 + tid;
      int row = idx >> 3, seg = idx & 7;
      int sw = (seg ^ (row & 7)) << 3;
      load_lds16(A + (size_t)(m0 + row) * Kdim + k0 + sw, &As[row * 64 + seg * 8]);
      load_lds16(Bt + (size_t)(n0 + row) * Kdim + k0 + sw, &Bs[row * 64 + seg * 8]);
    }
    __syncthreads();

    bf16x8 af[4], bfr[4];
    // half 0: k = k0 + 0..31
#pragma unroll
    for (int i = 0; i < 4; ++i)
      af[i] = *reinterpret_cast<const bf16x8*>(&As[(wm + i * 16 + lrow) * 64 + x0]);
#pragma unroll
    for (int j = 0; j < 4; ++j)
      bfr[j] = *reinterpret_cast<const bf16x8*>(&Bs[(wn + j * 16 + lrow) * 64 + x0]);
#pragma unroll
    for (int i = 0; i < 4; ++i)
#pragma unroll
      for (int j = 0; j < 4; ++j)
        acc[i][j] = mfma16(af[i], bfr[j], acc[i][j]);
    // half 1: k = k0 + 32..63
#pragma unroll
    for (int i = 0; i < 4; ++i)
      af[i] = *reinterpret_cast<const bf16x8*>(&As[(wm + i * 16 + lrow) * 64 + x1]);
#pragma unroll
    for (int j = 0; j < 4; ++j)
      bfr[j] = *reinterpret_cast<const bf16x8*>(&Bs[(wn + j * 16 + lrow) * 64 + x1]);
#pragma unroll
    for (int i = 0; i < 4; ++i)
#pragma unroll
      for (int j = 0; j < 4; ++j)
        acc[i][j] = mfma16(af[i], bfr[j], acc[i][j]);
    __syncthreads();
  }

#pragma unroll
  for (int i = 0; i < 4; ++i) {
#pragma unroll
    for (int j = 0; j < 4; ++j) {
      int col = n0 + wn + j * 16 + lrow;
      float bv = bias[col];
#pragma unroll
      for (int r = 0; r < 4; ++r) {
        int row = m0 + wm + i * 16 + r4 + r;
        float v = acc[i][j][r] + bv;
        if (OUT_BF16) {
          ((unsigned short*)Cv)[(size_t)row * Ndim + col] = f2bfu(v);
        } else {
          ((float*)Cv)[(size_t)row * Ndim + col] = v;
        }
      }
    }
  }
}

// ---------------- Flash attention (exact R9: verified 77 us) ----------------
__global__ __launch_bounds__(256, 4) void attn_kernel(const unsigned short* __restrict__ mixed,
                                                      const unsigned short* __restrict__ vT,
                                                      const float* __restrict__ mask,
                                                      const unsigned char* __restrict__ flags,
                                                      unsigned short* __restrict__ ctx) {
  __shared__ __align__(16) unsigned short Ks[2][64 * 64];
  __shared__ __align__(16) unsigned short Vt[2][64 * 64];   // [d][s]
  __shared__ __align__(16) unsigned short QP[64 * 64];      // Q tile, then P (per-wave)

  const int tid = threadIdx.x, wave = tid >> 6, lane = tid & 63;
  const int ql = lane & 15;
  const int g = lane >> 4;
  const int q0 = blockIdx.x * 64;
  const int bh = blockIdx.y;
  const int b = bh / NHH, hh = bh % NHH;

  const unsigned short* qbase = mixed + (size_t)(b * SS) * N1 + hh * 192;
  const unsigned short* kbase = qbase + 64;
  const unsigned short* vtbase = vT + ((size_t)(b * NHH + hh) * HDD) * SS;  // [d][s]
  const float* mbase = mask + (size_t)b * SS * SS;
  const unsigned char* fl = flags + ((size_t)b * 32 + blockIdx.x) * 32;

  const int srow = tid >> 3, sseg = tid & 7;
  const int swst = (sseg ^ (srow & 7)) << 3;

  // ---- prologue: stage Q, K0, V0 ----
  load_lds16(qbase + (size_t)(q0 + srow) * N1 + swst, &QP[srow * 64 + sseg * 8]);
  load_lds16(qbase + (size_t)(q0 + 32 + srow) * N1 + swst, &QP[(32 + srow) * 64 + sseg * 8]);
  load_lds16(kbase + (size_t)srow * N1 + swst, &Ks[0][srow * 64 + sseg * 8]);
  load_lds16(kbase + (size_t)(32 + srow) * N1 + swst, &Ks[0][(32 + srow) * 64 + sseg * 8]);
  load_lds16(vtbase + (size_t)srow * SS + swst, &Vt[0][srow * 64 + sseg * 8]);
  load_lds16(vtbase + (size_t)(32 + srow) * SS + swst, &Vt[0][(32 + srow) * 64 + sseg * 8]);
  __syncthreads();

  // ---- hoist Q fragments ----
  const int qrow = wave * 16 + ql;
  const bf16x8 qf0 = *reinterpret_cast<const bf16x8*>(
      &QP[qrow * 64 + ((g ^ (qrow & 7)) << 3)]);
  const bf16x8 qf1 = *reinterpret_cast<const bf16x8*>(
      &QP[qrow * 64 + (((g + 4) ^ (qrow & 7)) << 3)]);
  __syncthreads();   // everyone done reading Q before P overwrites it

  // ---- precomputed loop-invariant LDS pointers ----
  const int s0 = (g ^ (ql & 7)) << 3;
  const int s1 = ((g + 4) ^ (ql & 7)) << 3;
  const unsigned short* KrA = &Ks[0][ql * 64 + s0];   // + CUR*4096 + n*1024
  const unsigned short* KrB = &Ks[0][ql * 64 + s1];
  const unsigned short* VrA = &Vt[0][ql * 64 + s0];   // + CUR*4096 + fd*1024
  const unsigned short* VrB = &Vt[0][ql * 64 + s1];
  unsigned short* Ps = &QP[wave * 1024];
  const int X = (ql & 7) << 3;
  unsigned short* Pw0 = &Ps[ql * 64 + ((4 * g) ^ X)];
  unsigned short* Pw1 = &Ps[ql * 64 + ((16 + 4 * g) ^ X)];
  unsigned short* Pw2 = &Ps[ql * 64 + ((32 + 4 * g) ^ X)];
  unsigned short* Pw3 = &Ps[ql * 64 + ((48 + 4 * g) ^ X)];
  const unsigned short* Pr0 = &Ps[ql * 64 + ((8 * g) ^ X)];
  const unsigned short* Pr1 = &Ps[ql * 64 + ((32 + 8 * g) ^ X)];

  // ---- loop-carried global prefetch pointers ----
  const unsigned short* kpre = kbase + (size_t)(64 + srow) * N1 + swst;
  const unsigned short* vpre = vtbase + (size_t)srow * SS + 64 + swst;

  f32x4 oacc[4];
  const f32x4 z = {0.f, 0.f, 0.f, 0.f};
  for (int fd = 0; fd < 4; ++fd) oacc[fd] = z;
  float lsum = 0.f;
  const float C2 = 0.125f * LOG2E;

#define TILE_BODY(CUR_, KT_, HAVENEXT_)                                         \
  {                                                                             \
    const int kt_ = (KT_);                                                      \
    if (HAVENEXT_) {                                                            \
      load_lds16(kpre, &Ks[(CUR_)^1][srow * 64 + sseg * 8]);                    \
      load_lds16(kpre + 32 * N1, &Ks[(CUR_)^1][(32 + srow) * 64 + sseg * 8]);   \
      load_lds16(vpre, &Vt[(CUR_)^1][srow * 64 + sseg * 8]);                    \
      load_lds16(vpre + 32 * SS, &Vt[(CUR_)^1][(32 + srow) * 64 + sseg * 8]);   \
    }                                                                           \
    kpre += 64 * N1; vpre += 64;                                                \
    f32x4 sacc[4];                                                              \
    __builtin_amdgcn_s_setprio(1);                                              \
    _Pragma("unroll")                                                           \
    for (int n = 0; n < 4; ++n) {                                               \
      bf16x8 k0 = *reinterpret_cast<const bf16x8*>(KrA + (CUR_)*4096 + n*1024); \
      bf16x8 k1 = *reinterpret_cast<const bf16x8*>(KrB + (CUR_)*4096 + n*1024); \
      sacc[n] = mfma16(k0, qf0, z);                                             \
      sacc[n] = mfma16(k1, qf1, sacc[n]);                                       \
    }                                                                           \
    __builtin_amdgcn_s_setprio(0);                                              \
    const bool allones = fl[kt_] != 0;                                          \
    float pv[4][4];                                                             \
    if (allones) {                                                              \
      _Pragma("unroll")                                                         \
      for (int n = 0; n < 4; ++n)                                               \
        _Pragma("unroll")                                                       \
        for (int r = 0; r < 4; ++r)                                             \
          pv[n][r] = exp2f(sacc[n][r] * C2);                                    \
    } else {                                                                    \
      int qq = q0 + wave * 16 + ql;                                             \
      _Pragma("unroll")                                                         \
      for (int n = 0; n < 4; ++n)                                               \
        _Pragma("unroll")                                                       \
        for (int r = 0; r < 4; ++r) {                                           \
          int kk = kt_ * 64 + 16 * n + 4 * g + r;                               \
          float mv = mbase[(size_t)qq * SS + kk];                               \
          float s = sacc[n][r] * 0.125f;                                        \
          pv[n][r] = exp2f((s * mv - 10000.f * (1.f - mv)) * LOG2E);            \
        }                                                                       \
    }                                                                           \
    {                                                                           \
      float t00 = (pv[0][0] + pv[0][1]) + (pv[0][2] + pv[0][3]);                \
      float t01 = (pv[1][0] + pv[1][1]) + (pv[1][2] + pv[1][3]);                \
      float t10 = (pv[2][0] + pv[2][1]) + (pv[2][2] + pv[2][3]);                \
      float t11 = (pv[3][0] + pv[3][1]) + (pv[3][2] + pv[3][3]);                \
      lsum += (t00 + t01) + (t10 + t11);                                        \
    }                                                                           \
    { uint2 w; w.x = cvtpk(pv[0][0], pv[0][1]); w.y = cvtpk(pv[0][2], pv[0][3]);\
      *reinterpret_cast<uint2*>(Pw0) = w; }                                     \
    { uint2 w; w.x = cvtpk(pv[1][0], pv[1][1]); w.y = cvtpk(pv[1][2], pv[1][3]);\
      *reinterpret_cast<uint2*>(Pw1) = w; }                                     \
    { uint2 w; w.x = cvtpk(pv[2][0], pv[2][1]); w.y = cvtpk(pv[2][2], pv[2][3]);\
      *reinterpret_cast<uint2*>(Pw2) = w; }                                     \
    { uint2 w; w.x = cvtpk(pv[3][0], pv[3][1]); w.y = cvtpk(pv[3][2], pv[3][3]);\
      *reinterpret_cast<uint2*>(Pw3) = w; }                                     \
    bf16x8 pa0 = *reinterpret_cast<const bf16x8*>(Pr0);                         \
    bf16x8 pa1 = *reinterpret_cast<const bf16x8*>(Pr1);                         \
    __builtin_amdgcn_s_setprio(1);                                              \
    _Pragma("unroll")                                                           \
    for (int fd = 0; fd < 4; ++fd) {                                            \
      bf16x8 bv0 = *reinterpret_cast<const bf16x8*>(VrA + (CUR_)*4096 + fd*1024);\
      bf16x8 bv1 = *reinterpret_cast<const bf16x8*>(VrB + (CUR_)*4096 + fd*1024);\
      oacc[fd] = mfma16(pa0, bv0, oacc[fd]);                                    \
      oacc[fd] = mfma16(pa1, bv1, oacc[fd]);                                    \
    }                                                                           \
    __builtin_amdgcn_s_setprio(0);                                              \
    __syncthreads();                                                            \
  }

  for (int kt = 0; kt < NT; kt += 2) {
    TILE_BODY(0, kt, true)                 // kt <= 30 -> kt+1 < 32 always
    TILE_BODY(1, kt + 1, (kt + 2 < NT))
  }
#undef TILE_BODY

  // ---- epilogue: reduce l across groups, gather per-row, store ----
  float lrun = lsum;
  lrun += __shfl_xor(lrun, 16, 64);
  lrun += __shfl_xor(lrun, 32, 64);
  float invl = 1.f / lrun;   // valid for q = ql at this lane
#pragma unroll
  for (int r = 0; r < 4; ++r) {
    float inv = __shfl(invl, g * 4 + r, 64);
    int qq = q0 + wave * 16 + g * 4 + r;
    unsigned short* cp = ctx + (size_t)(b * SS + qq) * HH + hh * HDD;
#pragma unroll
    for (int fd = 0; fd < 4; ++fd)
      cp[fd * 16 + ql] = f2bfu(oacc[fd][r] * inv);
  }
}

extern "C" void kernel_launch(void* const* d_in, const int* in_sizes, int n_in,
                              void* d_out, int out_size, void* d_ws, size_t ws_size,
                              hipStream_t stream) {
  const float* hs      = (const float*)d_in[0];
  const float* mask    = (const float*)d_in[1];
  const float* qkv_w   = (const float*)d_in[2];
  const float* qkv_b   = (const float*)d_in[3];
  const float* dense_w = (const float*)d_in[4];
  const float* dense_b = (const float*)d_in[5];
  float* out = (float*)d_out;

  char* ws = (char*)d_ws;
  unsigned short* hs_b     = (unsigned short*)(ws);                 // 4096x1024 (8MB)
  unsigned short* qkvw_b   = (unsigned short*)(ws + 8388608);       // 3072x1024 (6MB)
  unsigned short* densew_b = (unsigned short*)(ws + 14680064);      // 1024x1024 (2MB)
  unsigned short* mixed_b  = (unsigned short*)(ws + 16777216);      // 4096x3072 (24MB)
  unsigned short* ctx_b    = (unsigned short*)(ws + 41943040);      // 4096x1024 (8MB)
  unsigned char*  flags    = (unsigned char*)(ws + 50331648);       // 2048 B
  unsigned short* vT_b     = (unsigned short*)(ws + 50335744);      // 8MB

  cvt3_f32_bf16<<<2048, 256, 0, stream>>>(hs, hs_b, (MM * HH) / 4,
                                          qkv_w, qkvw_b, (N1 * HH) / 4,
                                          dense_w, densew_b, (HH * HH) / 4);
  mask_flags_kernel<<<BB * 32 * 32, 256, 0, stream>>>(mask, flags);

  gemm_bt<true><<<dim3(MM / 128, N1 / 128), 256, 0, stream>>>(
      hs_b, qkvw_b, qkv_b, mixed_b, N1, HH);

  vtrans_kernel<<<dim3(SS / 64, BB * NHH), 256, 0, stream>>>(mixed_b, vT_b);

  attn_kernel<<<dim3(SS / 64, BB * NHH), 256, 0, stream>>>(
      mixed_b, vT_b, mask, flags, ctx_b);

  gemm_bt<false><<<dim3(MM / 128, HH / 128), 256, 0, stream>>>(
      ctx_b, densew_b, dense_b, out, HH, HH);
}

// Round 14
// 149.200 us; speedup vs baseline: 2.1253x; 1.0005x over previous
//
#include <hip/hip_runtime.h>
#include <hip/hip_bf16.h>
#include <stdint.h>

#define BB 2
#define SS 2048
#define HH 1024
#define NHH 16
#define HDD 64
#define MM (BB*SS)      // 4096
#define N1 (3*HH)       // 3072
#define NT (SS/64)      // 32 kv tiles
#define LOG2E 1.44269504f

using bf16 = __hip_bfloat16;
typedef __attribute__((ext_vector_type(8))) short bf16x8;
typedef __attribute__((ext_vector_type(4))) float f32x4;

__device__ inline unsigned short f2bfu(float f) {
  union { bf16 h; unsigned short u; } c;
  c.h = __float2bfloat16(f);
  return c.u;
}

// hardware packed f32->bf16 (RNE), src0 -> low16, src1 -> high16 (T12 recipe)
__device__ inline unsigned int cvtpk(float lo, float hi) {
  unsigned int r;
  asm("v_cvt_pk_bf16_f32 %0, %1, %2" : "=v"(r) : "v"(lo), "v"(hi));
  return r;
}

__device__ inline void load_lds16(const void* g, void* l) {
  __builtin_amdgcn_global_load_lds(
      (const __attribute__((address_space(1))) void*)g,
      (__attribute__((address_space(3))) void*)l, 16, 0, 0);
}

__device__ inline f32x4 mfma16(bf16x8 a, bf16x8 b, f32x4 c) {
  return __builtin_amdgcn_mfma_f32_16x16x32_bf16(a, b, c, 0, 0, 0);
}

// ---------------- fused fp32 -> bf16 convert (3 buffers, one launch) ----------------
__global__ __launch_bounds__(256) void cvt3_f32_bf16(const float* __restrict__ a,
                                                     unsigned short* __restrict__ ao, int na4,
                                                     const float* __restrict__ bsrc,
                                                     unsigned short* __restrict__ bo, int nb4,
                                                     const float* __restrict__ c,
                                                     unsigned short* __restrict__ co, int nc4) {
  int total = na4 + nb4 + nc4;
  int st = gridDim.x * blockDim.x;
  for (int i = blockIdx.x * blockDim.x + threadIdx.x; i < total; i += st) {
    const float* in; unsigned short* out; int j = i;
    if (j < na4) { in = a; out = ao; }
    else if (j < na4 + nb4) { j -= na4; in = bsrc; out = bo; }
    else { j -= na4 + nb4; in = c; out = co; }
    float4 v = reinterpret_cast<const float4*>(in)[j];
    ushort4 o;
    o.x = f2bfu(v.x); o.y = f2bfu(v.y); o.z = f2bfu(v.z); o.w = f2bfu(v.w);
    reinterpret_cast<ushort4*>(out)[j] = o;
  }
}

// ---------------- mask tile flags: 1 if 64x64 tile is all ones ----------------
__global__ __launch_bounds__(256) void mask_flags_kernel(const float* __restrict__ mask,
                                                         unsigned char* __restrict__ flags) {
  int t = blockIdx.x;
  int b = t >> 10, qt = (t >> 5) & 31, kt = t & 31;
  const float* mb = mask + ((size_t)b * SS + qt * 64) * SS + kt * 64;
  int row = threadIdx.x >> 2, c0 = (threadIdx.x & 3) * 16;
  int ok = 1;
#pragma unroll
  for (int j = 0; j < 4; ++j) {
    float4 v = *reinterpret_cast<const float4*>(mb + (size_t)row * SS + c0 + j * 4);
    ok &= (v.x == 1.f) & (v.y == 1.f) & (v.z == 1.f) & (v.w == 1.f);
  }
  ok = __all(ok);
  __shared__ int s[4];
  if ((threadIdx.x & 63) == 0) s[threadIdx.x >> 6] = ok;
  __syncthreads();
  if (threadIdx.x == 0) flags[t] = (unsigned char)(s[0] & s[1] & s[2] & s[3]);
}

// ---------------- V transpose: mixed V-cols -> vT[b][h][d][s] ----------------
__global__ __launch_bounds__(256) void vtrans_kernel(const unsigned short* __restrict__ mixed,
                                                     unsigned short* __restrict__ vT) {
  __shared__ unsigned short t[64 * 72];
  const int st = blockIdx.x, bh = blockIdx.y;
  const int b = bh >> 4, h = bh & 15;
  const int r = threadIdx.x >> 2, c0 = (threadIdx.x & 3) * 16;

  const unsigned short* src = mixed + ((size_t)(b * SS) + st * 64) * N1 + h * 192 + 128;
  union { bf16x8 v; unsigned short u[8]; } A, B;
  A.v = *reinterpret_cast<const bf16x8*>(src + (size_t)r * N1 + c0);
  B.v = *reinterpret_cast<const bf16x8*>(src + (size_t)r * N1 + c0 + 8);
#pragma unroll
  for (int j = 0; j < 8; ++j) t[(c0 + j) * 72 + r] = A.u[j];
#pragma unroll
  for (int j = 0; j < 8; ++j) t[(c0 + 8 + j) * 72 + r] = B.u[j];
  __syncthreads();

  unsigned short* dst = vT + ((size_t)bh * HDD + r) * SS + st * 64 + c0;
  bf16x8 o0 = *reinterpret_cast<const bf16x8*>(&t[r * 72 + c0]);
  bf16x8 o1 = *reinterpret_cast<const bf16x8*>(&t[r * 72 + c0 + 8]);
  *reinterpret_cast<bf16x8*>(dst) = o0;
  *reinterpret_cast<bf16x8*>(dst + 8) = o1;
}

// ---------------- GEMM: C[m][n] = sum_k A[m][k]*Bt[n][k] + bias[n] ----------------
// 128x128 tile, BK=64 (half the barriers of BK=32), XOR-swizzled LDS (same
// verified pattern as attn staging): stage source col-seg pre-XORed with row&7,
// fragment reads XOR with lrow&7 (row&7 == lrow&7 since 16 | (wm + i*16)).
template <bool OUT_BF16>
__global__ __launch_bounds__(256) void gemm_bt(const unsigned short* __restrict__ A,
                                               const unsigned short* __restrict__ Bt,
                                               const float* __restrict__ bias,
                                               void* __restrict__ Cv,
                                               int Ndim, int Kdim) {
  __shared__ __align__(16) unsigned short As[128 * 64];
  __shared__ __align__(16) unsigned short Bs[128 * 64];

  const int tid = threadIdx.x;
  const int wave = tid >> 6, lane = tid & 63;
  const int m0 = blockIdx.x * 128;
  const int n0 = blockIdx.y * 128;
  const int wm = (wave >> 1) * 64, wn = (wave & 1) * 64;
  const int lrow = lane & 15;
  const int g = lane >> 4;            // 0..3 col-seg group
  const int r4 = (lane >> 4) * 4;
  const int x0 = (g ^ (lrow & 7)) << 3;        // half-0 read seg offset (elems)
  const int x1 = ((g + 4) ^ (lrow & 7)) << 3;  // half-1

  f32x4 acc[4][4];
  const f32x4 z = {0.f, 0.f, 0.f, 0.f};
  for (int i = 0; i < 4; ++i)
    for (int j = 0; j < 4; ++j) acc[i][j] = z;

  for (int k0 = 0; k0 < Kdim; k0 += 64) {
#pragma unroll
    for (int it = 0; it < 4; ++it) {
      int idx = it * 256 + tid;
      int row = idx >> 3, seg = idx & 7;
      int sw = (seg ^ (row & 7)) << 3;
      load_lds16(A + (size_t)(m0 + row) * Kdim + k0 + sw, &As[row * 64 + seg * 8]);
      load_lds16(Bt + (size_t)(n0 + row) * Kdim + k0 + sw, &Bs[row * 64 + seg * 8]);
    }
    __syncthreads();

    bf16x8 af[4], bfr[4];
    // half 0: k = k0 + 0..31
#pragma unroll
    for (int i = 0; i < 4; ++i)
      af[i] = *reinterpret_cast<const bf16x8*>(&As[(wm + i * 16 + lrow) * 64 + x0]);
#pragma unroll
    for (int j = 0; j < 4; ++j)
      bfr[j] = *reinterpret_cast<const bf16x8*>(&Bs[(wn + j * 16 + lrow) * 64 + x0]);
#pragma unroll
    for (int i = 0; i < 4; ++i)
#pragma unroll
      for (int j = 0; j < 4; ++j)
        acc[i][j] = mfma16(af[i], bfr[j], acc[i][j]);
    // half 1: k = k0 + 32..63
#pragma unroll
    for (int i = 0; i < 4; ++i)
      af[i] = *reinterpret_cast<const bf16x8*>(&As[(wm + i * 16 + lrow) * 64 + x1]);
#pragma unroll
    for (int j = 0; j < 4; ++j)
      bfr[j] = *reinterpret_cast<const bf16x8*>(&Bs[(wn + j * 16 + lrow) * 64 + x1]);
#pragma unroll
    for (int i = 0; i < 4; ++i)
#pragma unroll
      for (int j = 0; j < 4; ++j)
        acc[i][j] = mfma16(af[i], bfr[j], acc[i][j]);
    __syncthreads();
  }

#pragma unroll
  for (int i = 0; i < 4; ++i) {
#pragma unroll
    for (int j = 0; j < 4; ++j) {
      int col = n0 + wn + j * 16 + lrow;
      float bv = bias[col];
#pragma unroll
      for (int r = 0; r < 4; ++r) {
        int row = m0 + wm + i * 16 + r4 + r;
        float v = acc[i][j][r] + bv;
        if (OUT_BF16) {
          ((unsigned short*)Cv)[(size_t)row * Ndim + col] = f2bfu(v);
        } else {
          ((float*)Cv)[(size_t)row * Ndim + col] = v;
        }
      }
    }
  }
}

// ---------------- Flash attention (exact R9: verified 77 us) ----------------
__global__ __launch_bounds__(256, 4) void attn_kernel(const unsigned short* __restrict__ mixed,
                                                      const unsigned short* __restrict__ vT,
                                                      const float* __restrict__ mask,
                                                      const unsigned char* __restrict__ flags,
                                                      unsigned short* __restrict__ ctx) {
  __shared__ __align__(16) unsigned short Ks[2][64 * 64];
  __shared__ __align__(16) unsigned short Vt[2][64 * 64];   // [d][s]
  __shared__ __align__(16) unsigned short QP[64 * 64];      // Q tile, then P (per-wave)

  const int tid = threadIdx.x, wave = tid >> 6, lane = tid & 63;
  const int ql = lane & 15;
  const int g = lane >> 4;
  const int q0 = blockIdx.x * 64;
  const int bh = blockIdx.y;
  const int b = bh / NHH, hh = bh % NHH;

  const unsigned short* qbase = mixed + (size_t)(b * SS) * N1 + hh * 192;
  const unsigned short* kbase = qbase + 64;
  const unsigned short* vtbase = vT + ((size_t)(b * NHH + hh) * HDD) * SS;  // [d][s]
  const float* mbase = mask + (size_t)b * SS * SS;
  const unsigned char* fl = flags + ((size_t)b * 32 + blockIdx.x) * 32;

  const int srow = tid >> 3, sseg = tid & 7;
  const int swst = (sseg ^ (srow & 7)) << 3;

  // ---- prologue: stage Q, K0, V0 ----
  load_lds16(qbase + (size_t)(q0 + srow) * N1 + swst, &QP[srow * 64 + sseg * 8]);
  load_lds16(qbase + (size_t)(q0 + 32 + srow) * N1 + swst, &QP[(32 + srow) * 64 + sseg * 8]);
  load_lds16(kbase + (size_t)srow * N1 + swst, &Ks[0][srow * 64 + sseg * 8]);
  load_lds16(kbase + (size_t)(32 + srow) * N1 + swst, &Ks[0][(32 + srow) * 64 + sseg * 8]);
  load_lds16(vtbase + (size_t)srow * SS + swst, &Vt[0][srow * 64 + sseg * 8]);
  load_lds16(vtbase + (size_t)(32 + srow) * SS + swst, &Vt[0][(32 + srow) * 64 + sseg * 8]);
  __syncthreads();

  // ---- hoist Q fragments ----
  const int qrow = wave * 16 + ql;
  const bf16x8 qf0 = *reinterpret_cast<const bf16x8*>(
      &QP[qrow * 64 + ((g ^ (qrow & 7)) << 3)]);
  const bf16x8 qf1 = *reinterpret_cast<const bf16x8*>(
      &QP[qrow * 64 + (((g + 4) ^ (qrow & 7)) << 3)]);
  __syncthreads();   // everyone done reading Q before P overwrites it

  // ---- precomputed loop-invariant LDS pointers ----
  const int s0 = (g ^ (ql & 7)) << 3;
  const int s1 = ((g + 4) ^ (ql & 7)) << 3;
  const unsigned short* KrA = &Ks[0][ql * 64 + s0];   // + CUR*4096 + n*1024
  const unsigned short* KrB = &Ks[0][ql * 64 + s1];
  const unsigned short* VrA = &Vt[0][ql * 64 + s0];   // + CUR*4096 + fd*1024
  const unsigned short* VrB = &Vt[0][ql * 64 + s1];
  unsigned short* Ps = &QP[wave * 1024];
  const int X = (ql & 7) << 3;
  unsigned short* Pw0 = &Ps[ql * 64 + ((4 * g) ^ X)];
  unsigned short* Pw1 = &Ps[ql * 64 + ((16 + 4 * g) ^ X)];
  unsigned short* Pw2 = &Ps[ql * 64 + ((32 + 4 * g) ^ X)];
  unsigned short* Pw3 = &Ps[ql * 64 + ((48 + 4 * g) ^ X)];
  const unsigned short* Pr0 = &Ps[ql * 64 + ((8 * g) ^ X)];
  const unsigned short* Pr1 = &Ps[ql * 64 + ((32 + 8 * g) ^ X)];

  // ---- loop-carried global prefetch pointers ----
  const unsigned short* kpre = kbase + (size_t)(64 + srow) * N1 + swst;
  const unsigned short* vpre = vtbase + (size_t)srow * SS + 64 + swst;

  f32x4 oacc[4];
  const f32x4 z = {0.f, 0.f, 0.f, 0.f};
  for (int fd = 0; fd < 4; ++fd) oacc[fd] = z;
  float lsum = 0.f;
  const float C2 = 0.125f * LOG2E;

#define TILE_BODY(CUR_, KT_, HAVENEXT_)                                         \
  {                                                                             \
    const int kt_ = (KT_);                                                      \
    if (HAVENEXT_) {                                                            \
      load_lds16(kpre, &Ks[(CUR_)^1][srow * 64 + sseg * 8]);                    \
      load_lds16(kpre + 32 * N1, &Ks[(CUR_)^1][(32 + srow) * 64 + sseg * 8]);   \
      load_lds16(vpre, &Vt[(CUR_)^1][srow * 64 + sseg * 8]);                    \
      load_lds16(vpre + 32 * SS, &Vt[(CUR_)^1][(32 + srow) * 64 + sseg * 8]);   \
    }                                                                           \
    kpre += 64 * N1; vpre += 64;                                                \
    f32x4 sacc[4];                                                              \
    __builtin_amdgcn_s_setprio(1);                                              \
    _Pragma("unroll")                                                           \
    for (int n = 0; n < 4; ++n) {                                               \
      bf16x8 k0 = *reinterpret_cast<const bf16x8*>(KrA + (CUR_)*4096 + n*1024); \
      bf16x8 k1 = *reinterpret_cast<const bf16x8*>(KrB + (CUR_)*4096 + n*1024); \
      sacc[n] = mfma16(k0, qf0, z);                                             \
      sacc[n] = mfma16(k1, qf1, sacc[n]);                                       \
    }                                                                           \
    __builtin_amdgcn_s_setprio(0);                                              \
    const bool allones = fl[kt_] != 0;                                          \
    float pv[4][4];                                                             \
    if (allones) {                                                              \
      _Pragma("unroll")                                                         \
      for (int n = 0; n < 4; ++n)                                               \
        _Pragma("unroll")                                                       \
        for (int r = 0; r < 4; ++r)                                             \
          pv[n][r] = exp2f(sacc[n][r] * C2);                                    \
    } else {                                                                    \
      int qq = q0 + wave * 16 + ql;                                             \
      _Pragma("unroll")                                                         \
      for (int n = 0; n < 4; ++n)                                               \
        _Pragma("unroll")                                                       \
        for (int r = 0; r < 4; ++r) {                                           \
          int kk = kt_ * 64 + 16 * n + 4 * g + r;                               \
          float mv = mbase[(size_t)qq * SS + kk];                               \
          float s = sacc[n][r] * 0.125f;                                        \
          pv[n][r] = exp2f((s * mv - 10000.f * (1.f - mv)) * LOG2E);            \
        }                                                                       \
    }                                                                           \
    {                                                                           \
      float t00 = (pv[0][0] + pv[0][1]) + (pv[0][2] + pv[0][3]);                \
      float t01 = (pv[1][0] + pv[1][1]) + (pv[1][2] + pv[1][3]);                \
      float t10 = (pv[2][0] + pv[2][1]) + (pv[2][2] + pv[2][3]);                \
      float t11 = (pv[3][0] + pv[3][1]) + (pv[3][2] + pv[3][3]);                \
      lsum += (t00 + t01) + (t10 + t11);                                        \
    }                                                                           \
    { uint2 w; w.x = cvtpk(pv[0][0], pv[0][1]); w.y = cvtpk(pv[0][2], pv[0][3]);\
      *reinterpret_cast<uint2*>(Pw0) = w; }                                     \
    { uint2 w; w.x = cvtpk(pv[1][0], pv[1][1]); w.y = cvtpk(pv[1][2], pv[1][3]);\
      *reinterpret_cast<uint2*>(Pw1) = w; }                                     \
    { uint2 w; w.x = cvtpk(pv[2][0], pv[2][1]); w.y = cvtpk(pv[2][2], pv[2][3]);\
      *reinterpret_cast<uint2*>(Pw2) = w; }                                     \
    { uint2 w; w.x = cvtpk(pv[3][0], pv[3][1]); w.y = cvtpk(pv[3][2], pv[3][3]);\
      *reinterpret_cast<uint2*>(Pw3) = w; }                                     \
    bf16x8 pa0 = *reinterpret_cast<const bf16x8*>(Pr0);                         \
    bf16x8 pa1 = *reinterpret_cast<const bf16x8*>(Pr1);                         \
    __builtin_amdgcn_s_setprio(1);                                              \
    _Pragma("unroll")                                                           \
    for (int fd = 0; fd < 4; ++fd) {                                            \
      bf16x8 bv0 = *reinterpret_cast<const bf16x8*>(VrA + (CUR_)*4096 + fd*1024);\
      bf16x8 bv1 = *reinterpret_cast<const bf16x8*>(VrB + (CUR_)*4096 + fd*1024);\
      oacc[fd] = mfma16(pa0, bv0, oacc[fd]);                                    \
      oacc[fd] = mfma16(pa1, bv1, oacc[fd]);                                    \
    }                                                                           \
    __builtin_amdgcn_s_setprio(0);                                              \
    __syncthreads();                                                            \
  }

  for (int kt = 0; kt < NT; kt += 2) {
    TILE_BODY(0, kt, true)                 // kt <= 30 -> kt+1 < 32 always
    TILE_BODY(1, kt + 1, (kt + 2 < NT))
  }
#undef TILE_BODY

  // ---- epilogue: reduce l across groups, gather per-row, store ----
  float lrun = lsum;
  lrun += __shfl_xor(lrun, 16, 64);
  lrun += __shfl_xor(lrun, 32, 64);
  float invl = 1.f / lrun;   // valid for q = ql at this lane
#pragma unroll
  for (int r = 0; r < 4; ++r) {
    float inv = __shfl(invl, g * 4 + r, 64);
    int qq = q0 + wave * 16 + g * 4 + r;
    unsigned short* cp = ctx + (size_t)(b * SS + qq) * HH + hh * HDD;
#pragma unroll
    for (int fd = 0; fd < 4; ++fd)
      cp[fd * 16 + ql] = f2bfu(oacc[fd][r] * inv);
  }
}

extern "C" void kernel_launch(void* const* d_in, const int* in_sizes, int n_in,
                              void* d_out, int out_size, void* d_ws, size_t ws_size,
                              hipStream_t stream) {
  const float* hs      = (const float*)d_in[0];
  const float* mask    = (const float*)d_in[1];
  const float* qkv_w   = (const float*)d_in[2];
  const float* qkv_b   = (const float*)d_in[3];
  const float* dense_w = (const float*)d_in[4];
  const float* dense_b = (const float*)d_in[5];
  float* out = (float*)d_out;

  char* ws = (char*)d_ws;
  unsigned short* hs_b     = (unsigned short*)(ws);                 // 4096x1024 (8MB)
  unsigned short* qkvw_b   = (unsigned short*)(ws + 8388608);       // 3072x1024 (6MB)
  unsigned short* densew_b = (unsigned short*)(ws + 14680064);      // 1024x1024 (2MB)
  unsigned short* mixed_b  = (unsigned short*)(ws + 16777216);      // 4096x3072 (24MB)
  unsigned short* ctx_b    = (unsigned short*)(ws + 41943040);      // 4096x1024 (8MB)
  unsigned char*  flags    = (unsigned char*)(ws + 50331648);       // 2048 B
  unsigned short* vT_b     = (unsigned short*)(ws + 50335744);      // 8MB

  cvt3_f32_bf16<<<2048, 256, 0, stream>>>(hs, hs_b, (MM * HH) / 4,
                                          qkv_w, qkvw_b, (N1 * HH) / 4,
                                          dense_w, densew_b, (HH * HH) / 4);
  mask_flags_kernel<<<BB * 32 * 32, 256, 0, stream>>>(mask, flags);

  gemm_bt<true><<<dim3(MM / 128, N1 / 128), 256, 0, stream>>>(
      hs_b, qkvw_b, qkv_b, mixed_b, N1, HH);

  vtrans_kernel<<<dim3(SS / 64, BB * NHH), 256, 0, stream>>>(mixed_b, vT_b);

  attn_kernel<<<dim3(SS / 64, BB * NHH), 256, 0, stream>>>(
      mixed_b, vT_b, mask, flags, ctx_b);

  gemm_bt<false><<<dim3(MM / 128, HH / 128), 256, 0, stream>>>(
      ctx_b, densew_b, dense_b, out, HH, HH);
}